// Round 19
// baseline (112.971 us; speedup 1.0000x reference)
//
#include <hip/hip_runtime.h>
#include <hip/hip_bf16.h>

// Sizes (fixed by the problem)
#define N_   32
#define L_   77
#define CT_  512
#define C_   512
#define HW_  1024
#define HEAD_ 16
#define DH_  32   // C/HEAD
#define NL_  (N_ * L_)     // 2464
#define NLP_ 2496          // padded to 39*64

typedef __attribute__((ext_vector_type(8))) short bf16x8;
typedef __attribute__((ext_vector_type(4))) short bf16x4;
typedef __attribute__((ext_vector_type(4))) float f32x4;

static __device__ __forceinline__ unsigned short f2bf(float f) {
    unsigned int u = __float_as_uint(f);
    unsigned int r = (u + 0x7fffu + ((u >> 16) & 1u)) >> 16;  // RNE
    return (unsigned short)r;
}

// ---------------------------------------------------------------------------
// Prep (EXACT R18): token -> tokT[nl][c] bf16, Wk/Wv -> Wkv bf16, bkv.
// grid = 288
// ---------------------------------------------------------------------------
__global__ __launch_bounds__(256) void prep_kernel(
    const float* __restrict__ token,
    const float* __restrict__ Wk, const float* __restrict__ bk,
    const float* __restrict__ Wv, const float* __restrict__ bv,
    unsigned short* __restrict__ tokT, unsigned short* __restrict__ Wkv,
    float* __restrict__ bkv)
{
    const int blk = blockIdx.x;
    const int t = threadIdx.x;
    if (blk < 256) {
        __shared__ float tile[64][81];
        const int n = blk >> 3, c0 = (blk & 7) * 64;
        const float* src = token + (size_t)n * (CT_ * L_) + (size_t)c0 * L_;
        for (int idx = t; idx < 64 * L_; idx += 256) {
            int cc = idx / L_, l = idx - cc * L_;
            tile[cc][l] = src[idx];
        }
        __syncthreads();
        for (int idx = t; idx < L_ * 16; idx += 256) {
            int l = idx >> 4, cq = (idx & 15) * 4;
            ushort4 h;
            h.x = f2bf(tile[cq + 0][l]);
            h.y = f2bf(tile[cq + 1][l]);
            h.z = f2bf(tile[cq + 2][l]);
            h.w = f2bf(tile[cq + 3][l]);
            *(ushort4*)&tokT[((size_t)(n * L_ + l)) * 512 + c0 + cq] = h;
        }
    } else {
        const int wb = blk - 256;
        const int m0 = wb * 32;
        for (int idx = t; idx < 32 * 128; idx += 256) {
            int mr = idx >> 7, c4 = (idx & 127) * 4;
            int m = m0 + mr;
            const float* src = (m < 512) ? (Wk + (size_t)m * 512 + c4)
                                         : (Wv + (size_t)(m - 512) * 512 + c4);
            float4 f = *(const float4*)src;
            ushort4 h; h.x = f2bf(f.x); h.y = f2bf(f.y); h.z = f2bf(f.z); h.w = f2bf(f.w);
            *(ushort4*)&Wkv[(size_t)m * 512 + c4] = h;
        }
        if (wb == 0) {
            for (int idx = t; idx < 1024; idx += 256)
                bkv[idx] = (idx < 512) ? bk[idx] : bv[idx - 512];
        }
    }
}

// ---------------------------------------------------------------------------
// Wq f32 -> Wqbf bf16, once (EXACT R18). grid = 16, block 256.
// ---------------------------------------------------------------------------
__global__ __launch_bounds__(256) void wconv_kernel(
    const float* __restrict__ Wq, unsigned short* __restrict__ Wqbf)
{
    const int m0 = blockIdx.x * 32;
    const int t = threadIdx.x;
    for (int idx = t; idx < 32 * 128; idx += 256) {
        int mr = idx >> 7, c4 = (idx & 127) * 4;
        float4 f = *(const float4*)&Wq[(size_t)(m0 + mr) * 512 + c4];
        ushort4 h; h.x = f2bf(f.x); h.y = f2bf(f.y); h.z = f2bf(f.z); h.w = f2bf(f.w);
        *(ushort4*)&Wqbf[(size_t)(m0 + mr) * 512 + c4] = h;
    }
}

// ---------------------------------------------------------------------------
// KV GEMM via bf16 MFMA (EXACT R18): kvbuf[nl][m], grid = 312
// ---------------------------------------------------------------------------
__global__ __launch_bounds__(256) void kvgemm_kernel(
    const unsigned short* __restrict__ tokT,
    const unsigned short* __restrict__ Wkv,
    const float* __restrict__ bkv,
    float* __restrict__ kvbuf)
{
    __shared__ unsigned char Ab[128 * 128];
    __shared__ unsigned char Bb[64 * 128];

    const int blk = blockIdx.x;
    const int mt = blk / 39, nt = blk % 39;
    const int m0 = mt * 128, nl0 = nt * 64;
    const int t = threadIdx.x;
    const int lane = t & 63, w = t >> 6;
    const int wr = w >> 1, wc = w & 1;

    f32x4 acc[4][2];
#pragma unroll
    for (int i = 0; i < 4; ++i)
#pragma unroll
        for (int j = 0; j < 2; ++j) acc[i][j] = (f32x4){0.f, 0.f, 0.f, 0.f};

    for (int c0 = 0; c0 < 512; c0 += 64) {
        __syncthreads();
#pragma unroll
        for (int s = 0; s < 4; ++s) {
            int idx = t + s * 256;
            int row = idx >> 3, k8 = idx & 7;
            bf16x8 v = *(const bf16x8*)&Wkv[(size_t)(m0 + row) * 512 + c0 + k8 * 8];
            *(bf16x8*)(Ab + row * 128 + ((k8 * 16) ^ ((row & 7) << 4))) = v;
        }
#pragma unroll
        for (int s = 0; s < 2; ++s) {
            int idx = t + s * 256;
            int row = idx >> 3, k8 = idx & 7;
            bf16x8 v = *(const bf16x8*)&tokT[(size_t)(nl0 + row) * 512 + c0 + k8 * 8];
            *(bf16x8*)(Bb + row * 128 + ((k8 * 16) ^ ((row & 7) << 4))) = v;
        }
        __syncthreads();

#pragma unroll
        for (int ks = 0; ks < 2; ++ks) {
            const int kb = ks * 64 + (lane >> 4) * 16;
            bf16x8 a[4], b[2];
#pragma unroll
            for (int i = 0; i < 4; ++i) {
                int row = wr * 64 + i * 16 + (lane & 15);
                a[i] = *(const bf16x8*)(Ab + row * 128 + (kb ^ ((row & 7) << 4)));
            }
#pragma unroll
            for (int j = 0; j < 2; ++j) {
                int row = wc * 32 + j * 16 + (lane & 15);
                b[j] = *(const bf16x8*)(Bb + row * 128 + (kb ^ ((row & 7) << 4)));
            }
#pragma unroll
            for (int i = 0; i < 4; ++i)
#pragma unroll
                for (int j = 0; j < 2; ++j)
                    acc[i][j] = __builtin_amdgcn_mfma_f32_16x16x32_bf16(
                        a[i], b[j], acc[i][j], 0, 0, 0);
        }
    }

#pragma unroll
    for (int i = 0; i < 4; ++i) {
        int m = m0 + wr * 64 + i * 16 + (lane >> 4) * 4;
        float4 bias = *(const float4*)&bkv[m];
#pragma unroll
        for (int j = 0; j < 2; ++j) {
            int nl = nl0 + wc * 32 + j * 16 + (lane & 15);
            float4 o;
            o.x = acc[i][j][0] + bias.x;
            o.y = acc[i][j][1] + bias.y;
            o.z = acc[i][j][2] + bias.z;
            o.w = acc[i][j][3] + bias.w;
            *(float4*)&kvbuf[(size_t)nl * 1024 + m] = o;
        }
    }
}

// ---------------------------------------------------------------------------
// Q projection v4: BARRIER-FREE K-loop.
// Full B-tile (64p x 512c bf16 = 64KB LDS, staged once, swizzle (p&63)<<4);
// A-frags read directly from L2-resident Wqbf (no A staging, no Ab).
// 8 waves, each computing 64o x 64p (acc[4][4]). grid = N*16, block 512.
// ---------------------------------------------------------------------------
__global__ __launch_bounds__(512) void qmfma_kernel(
    const float* __restrict__ feature,
    const unsigned short* __restrict__ Wqbf, const float* __restrict__ bq,
    unsigned short* __restrict__ qbuf)
{
    __shared__ unsigned char Bb[64 * 1024];  // 64 p-rows x 512 c bf16 (1KB/row)

    const int blk = blockIdx.x;
    const int pt = blk & 15;
    const int n  = blk >> 4;
    const int p0 = pt * 64;
    const int t = threadIdx.x;
    const int lane = t & 63, w = t >> 6;    // 8 waves, wave w owns o-strip w*64
    const int q15 = lane & 15, g = lane >> 4;

    // ---- stage B once: feature [c][p] f32 -> Bb[p][c] bf16, swizzled
    {
        const float* featn = feature + (size_t)n * C_ * HW_ + p0;
        int p  = t & 63;
        int cq = (t >> 6) * 64;              // 8 c-groups of 64
#pragma unroll
        for (int it = 0; it < 16; ++it) {
            int cl = cq + it * 4;
            const float* src = featn + (size_t)cl * HW_ + p;
            float f0 = src[0];
            float f1 = src[HW_];
            float f2 = src[2 * HW_];
            float f3 = src[3 * HW_];
            ushort4 h; h.x = f2bf(f0); h.y = f2bf(f1); h.z = f2bf(f2); h.w = f2bf(f3);
            *(ushort4*)(Bb + p * 1024 + ((cl * 2) ^ ((p & 63) << 4))) = h;
        }
    }
    __syncthreads();

    f32x4 acc[4][4];
#pragma unroll
    for (int i = 0; i < 4; ++i)
#pragma unroll
        for (int j = 0; j < 4; ++j) acc[i][j] = (f32x4){0.f, 0.f, 0.f, 0.f};

    const unsigned short* wbase = Wqbf + (size_t)(w * 64) * 512;

    for (int c0 = 0; c0 < 512; c0 += 64) {
#pragma unroll
        for (int ks = 0; ks < 2; ++ks) {
            const int cb = c0 * 2 + ks * 64 + g * 16;   // byte offset of k-chunk
            bf16x8 a[4], b[4];
#pragma unroll
            for (int i = 0; i < 4; ++i) {
                int row = i * 16 + q15;
                a[i] = *(const bf16x8*)&wbase[(size_t)row * 512 + c0 + ks * 32 + g * 8];
            }
#pragma unroll
            for (int j = 0; j < 4; ++j) {
                int prow = j * 16 + q15;
                b[j] = *(const bf16x8*)(Bb + prow * 1024 + (cb ^ ((prow & 63) << 4)));
            }
#pragma unroll
            for (int i = 0; i < 4; ++i)
#pragma unroll
                for (int j = 0; j < 4; ++j)
                    acc[i][j] = __builtin_amdgcn_mfma_f32_16x16x32_bf16(
                        a[i], b[j], acc[i][j], 0, 0, 0);
        }
    }

    // epilogue (measured-fast form): scalar stores to qbuf[n][o][p]
    const float scale = 0.17677669529663687f;  // 1/sqrt(32)
#pragma unroll
    for (int i = 0; i < 4; ++i) {
#pragma unroll
        for (int r = 0; r < 4; ++r) {
            int o = w * 64 + i * 16 + (lane >> 4) * 4 + r;
            float bias = bq[o];
#pragma unroll
            for (int j = 0; j < 4; ++j) {
                int p = p0 + j * 16 + q15;
                qbuf[((size_t)n * C_ + o) * HW_ + p] = f2bf((acc[i][j][r] + bias) * scale);
            }
        }
    }
}

// ---------------------------------------------------------------------------
// Attention via MFMA (EXACT R18). grid = N*HEAD*4, block 256.
// ---------------------------------------------------------------------------
__global__ __launch_bounds__(256) void attn_kernel(
    const float* __restrict__ feature,
    const float* __restrict__ kvbuf,
    const unsigned short* __restrict__ qbuf,
    float* __restrict__ out)
{
    __shared__ unsigned char kl[80 * 64];    // K bf16 [l][32d], XOR-swizzled
    __shared__ unsigned char vt[32 * 176];   // V bf16 [d][88l]
    __shared__ unsigned char qs[256 * 64];   // Q bf16 [p][32o], chunk-XOR

    const int blk = blockIdx.x;
    const int pc = blk & 3;
    const int h  = (blk >> 2) & 15;
    const int n  = blk >> 6;
    const int t = threadIdx.x;
    const int lane = t & 63, w = t >> 6;
    const int q15 = lane & 15, g = lane >> 4;
    const int pb = pc * 256;        // block p base
    const int p0 = pb + w * 64;     // wave p base

    // ---- stage Q: qbuf rows [o][p] -> qs[p][o] (chunk-XOR swizzled)
    {
        const unsigned short* qsrc =
            qbuf + ((size_t)n * C_ + h * DH_) * HW_ + pb;
#pragma unroll
        for (int it = 0; it < 4; ++it) {
            int idx = t + it * 256;           // 0..1023
            int oo = idx >> 5;                // 0..31
            int p8 = (idx & 31) * 8;          // 0..248
            bf16x8 v = *(const bf16x8*)(qsrc + (size_t)oo * HW_ + p8);
            int key = ((p8 >> 3) & 3) << 4;   // per-8-row chunk rotation
            int slot = (((oo >> 3) << 4) ^ key) + (oo & 7) * 2;
            union { bf16x8 v8; unsigned short us[8]; } u; u.v8 = v;
#pragma unroll
            for (int j = 0; j < 8; ++j)
                *(unsigned short*)(qs + (p8 + j) * 64 + slot) = u.us[j];
        }
    }

    // zero padding tails
    if (t < 48) *(unsigned int*)(kl + 77 * 64 + t * 4) = 0;   // K rows 77..79
    if (t >= 96 && t < 96 + 352) {                            // V cols 77..87
        int u = t - 96;
        int d = u / 11, l = 77 + u % 11;
        *(unsigned short*)(vt + d * 176 + l * 2) = 0;
    }

    // stage K (swizzled [l][d]) and V (transposed [d][l])
    const float* kvb = kvbuf + (size_t)(n * L_) * 1024 + h * DH_;
    for (int idx = t; idx < L_ * 8; idx += 256) {
        int l = idx >> 3, dq = idx & 7;
        float4 k4 = *(const float4*)&kvb[(size_t)l * 1024 + dq * 4];
        ushort4 hk; hk.x = f2bf(k4.x); hk.y = f2bf(k4.y); hk.z = f2bf(k4.z); hk.w = f2bf(k4.w);
        int cx = dq >> 1, sub = (dq & 1) * 8;
        *(ushort4*)(kl + l * 64 + (((cx ^ (l & 3)) << 4) + sub)) = hk;
        float4 v4 = *(const float4*)&kvb[(size_t)l * 1024 + 512 + dq * 4];
        *(unsigned short*)(vt + (dq * 4 + 0) * 176 + l * 2) = f2bf(v4.x);
        *(unsigned short*)(vt + (dq * 4 + 1) * 176 + l * 2) = f2bf(v4.y);
        *(unsigned short*)(vt + (dq * 4 + 2) * 176 + l * 2) = f2bf(v4.z);
        *(unsigned short*)(vt + (dq * 4 + 3) * 176 + l * 2) = f2bf(v4.w);
    }
    __syncthreads();

    // Q B-frags from qs
    bf16x8 qf[4];
#pragma unroll
    for (int i = 0; i < 4; ++i) {
        int p = w * 64 + i * 16 + q15;
        qf[i] = *(const bf16x8*)(qs + p * 64 + ((g ^ ((p >> 3) & 3)) << 4));
    }
    // K A-frags: row l = lt*16 + q15, k-chunk = g
    bf16x8 kf[5];
#pragma unroll
    for (int lt = 0; lt < 5; ++lt) {
        int l = lt * 16 + q15;
        kf[lt] = *(const bf16x8*)(kl + l * 64 + ((g ^ (l & 3)) << 4));
    }
    // V B-frags (16x16x16): col d = dt*16 + q15, k = lt*16 + g*4 .. +3
    bf16x4 vf[5][2];
#pragma unroll
    for (int lt = 0; lt < 5; ++lt)
#pragma unroll
        for (int dt = 0; dt < 2; ++dt)
            vf[lt][dt] = *(const bf16x4*)(vt + (dt * 16 + q15) * 176 + lt * 32 + g * 8);

    const float* featn = feature + ((size_t)n * C_ + h * DH_) * HW_;
    float* outn = out + ((size_t)n * C_ + h * DH_) * HW_;

#pragma unroll
    for (int i = 0; i < 4; ++i) {
        f32x4 s[5];
#pragma unroll
        for (int lt = 0; lt < 5; ++lt)
            s[lt] = __builtin_amdgcn_mfma_f32_16x16x32_bf16(
                kf[lt], qf[i], (f32x4){0.f, 0.f, 0.f, 0.f}, 0, 0, 0);

#pragma unroll
        for (int r = 0; r < 4; ++r)
            if (4 * g + r >= 13) s[4][r] = -3.0e38f;

        float mx = s[0][0];
#pragma unroll
        for (int lt = 0; lt < 5; ++lt)
#pragma unroll
            for (int r = 0; r < 4; ++r) mx = fmaxf(mx, s[lt][r]);
        mx = fmaxf(mx, __shfl_xor(mx, 16));
        mx = fmaxf(mx, __shfl_xor(mx, 32));

        float Z = 0.f;
#pragma unroll
        for (int lt = 0; lt < 5; ++lt)
#pragma unroll
            for (int r = 0; r < 4; ++r) {
                float e = __expf(s[lt][r] - mx);
                s[lt][r] = e;
                Z += e;
            }
        Z += __shfl_xor(Z, 16);
        Z += __shfl_xor(Z, 32);
        const float inv = 1.f / Z;

        unsigned int pk[5][2];
#pragma unroll
        for (int lt = 0; lt < 5; ++lt) {
            pk[lt][0] = (unsigned int)f2bf(s[lt][0] * inv)
                      | ((unsigned int)f2bf(s[lt][1] * inv) << 16);
            pk[lt][1] = (unsigned int)f2bf(s[lt][2] * inv)
                      | ((unsigned int)f2bf(s[lt][3] * inv) << 16);
        }

        f32x4 pv[2];
        pv[0] = (f32x4){0.f, 0.f, 0.f, 0.f};
        pv[1] = (f32x4){0.f, 0.f, 0.f, 0.f};
#pragma unroll
        for (int lt = 0; lt < 5; ++lt) {
            union { unsigned int u[2]; bf16x4 v; } pa;
            pa.u[0] = pk[lt][0];
            pa.u[1] = pk[lt][1];
#pragma unroll
            for (int dt = 0; dt < 2; ++dt)
                pv[dt] = __builtin_amdgcn_mfma_f32_16x16x16bf16_1k(
                    pa.v, vf[lt][dt], pv[dt], 0, 0, 0);
        }

#pragma unroll
        for (int dt = 0; dt < 2; ++dt) {
            size_t off = (size_t)(dt * 16 + q15) * HW_ + p0 + i * 16 + g * 4;
            float4 f = *(const float4*)&featn[off];
            float4 o;
            o.x = f.x + pv[dt][0];
            o.y = f.y + pv[dt][1];
            o.z = f.z + pv[dt][2];
            o.w = f.w + pv[dt][3];
            *(float4*)&outn[off] = o;
        }
    }
}

// ---------------------------------------------------------------------------
extern "C" void kernel_launch(void* const* d_in, const int* in_sizes, int n_in,
                              void* d_out, int out_size, void* d_ws, size_t ws_size,
                              hipStream_t stream)
{
    const float* feature = (const float*)d_in[0];
    const float* token   = (const float*)d_in[1];
    const float* Wv      = (const float*)d_in[2];
    const float* bv      = (const float*)d_in[3];
    const float* Wk      = (const float*)d_in[4];
    const float* bk      = (const float*)d_in[5];
    const float* Wq      = (const float*)d_in[6];
    const float* bq      = (const float*)d_in[7];
    float* out = (float*)d_out;

    // workspace layout (R18)
    float* kvbuf = (float*)d_ws;                                   // NLP_*1024 f32
    unsigned short* tokT = (unsigned short*)(kvbuf + (size_t)NLP_ * 1024);  // NLP_*512 bf16
    unsigned short* Wkv  = tokT + (size_t)NLP_ * 512;              // 1024*512 bf16
    float* bkv = (float*)(Wkv + (size_t)1024 * 512);               // 1024 f32
    unsigned short* qbuf = (unsigned short*)(bkv + 1024);          // N*C*HW bf16 [n][o][p]
    unsigned short* Wqbf = qbuf + (size_t)N_ * C_ * HW_;           // 512*512 bf16

    prep_kernel<<<288, 256, 0, stream>>>(token, Wk, bk, Wv, bv, tokT, Wkv, bkv);
    wconv_kernel<<<16, 256, 0, stream>>>(Wq, Wqbf);
    kvgemm_kernel<<<312, 256, 0, stream>>>(tokT, Wkv, bkv, kvbuf);
    qmfma_kernel<<<N_ * 16, 512, 0, stream>>>(feature, Wqbf, bq, qbuf);
    attn_kernel<<<N_ * HEAD_ * 4, 256, 0, stream>>>(feature, kvbuf, qbuf, out);

    // tuple output: token passthrough
    hipMemcpyAsync(out + (size_t)N_ * C_ * HW_, token,
                   (size_t)N_ * L_ * CT_ * sizeof(float),
                   hipMemcpyDeviceToDevice, stream);
}

// Round 20
// 97.942 us; speedup vs baseline: 1.1534x; 1.1534x over previous
//
#include <hip/hip_runtime.h>
#include <hip/hip_bf16.h>

// Sizes (fixed by the problem)
#define N_   32
#define L_   77
#define CT_  512
#define C_   512
#define HW_  1024
#define HEAD_ 16
#define DH_  32   // C/HEAD
#define NL_  (N_ * L_)     // 2464
#define NLP_ 2496          // padded to 39*64

typedef __attribute__((ext_vector_type(8))) short bf16x8;
typedef __attribute__((ext_vector_type(4))) short bf16x4;
typedef __attribute__((ext_vector_type(4))) float f32x4;

static __device__ __forceinline__ unsigned short f2bf(float f) {
    unsigned int u = __float_as_uint(f);
    unsigned int r = (u + 0x7fffu + ((u >> 16) & 1u)) >> 16;  // RNE
    return (unsigned short)r;
}

// ---------------------------------------------------------------------------
// Prep: token -> tokT[nl][c] bf16, Wk/Wv -> Wkv bf16, bkv. grid = 288
// ---------------------------------------------------------------------------
__global__ __launch_bounds__(256) void prep_kernel(
    const float* __restrict__ token,
    const float* __restrict__ Wk, const float* __restrict__ bk,
    const float* __restrict__ Wv, const float* __restrict__ bv,
    unsigned short* __restrict__ tokT, unsigned short* __restrict__ Wkv,
    float* __restrict__ bkv)
{
    const int blk = blockIdx.x;
    const int t = threadIdx.x;
    if (blk < 256) {
        __shared__ float tile[64][81];
        const int n = blk >> 3, c0 = (blk & 7) * 64;
        const float* src = token + (size_t)n * (CT_ * L_) + (size_t)c0 * L_;
        for (int idx = t; idx < 64 * L_; idx += 256) {
            int cc = idx / L_, l = idx - cc * L_;
            tile[cc][l] = src[idx];
        }
        __syncthreads();
        for (int idx = t; idx < L_ * 16; idx += 256) {
            int l = idx >> 4, cq = (idx & 15) * 4;
            ushort4 h;
            h.x = f2bf(tile[cq + 0][l]);
            h.y = f2bf(tile[cq + 1][l]);
            h.z = f2bf(tile[cq + 2][l]);
            h.w = f2bf(tile[cq + 3][l]);
            *(ushort4*)&tokT[((size_t)(n * L_ + l)) * 512 + c0 + cq] = h;
        }
    } else {
        const int wb = blk - 256;
        const int m0 = wb * 32;
        for (int idx = t; idx < 32 * 128; idx += 256) {
            int mr = idx >> 7, c4 = (idx & 127) * 4;
            int m = m0 + mr;
            const float* src = (m < 512) ? (Wk + (size_t)m * 512 + c4)
                                         : (Wv + (size_t)(m - 512) * 512 + c4);
            float4 f = *(const float4*)src;
            ushort4 h; h.x = f2bf(f.x); h.y = f2bf(f.y); h.z = f2bf(f.z); h.w = f2bf(f.w);
            *(ushort4*)&Wkv[(size_t)m * 512 + c4] = h;
        }
        if (wb == 0) {
            for (int idx = t; idx < 1024; idx += 256)
                bkv[idx] = (idx < 512) ? bk[idx] : bv[idx - 512];
        }
    }
}

// ---------------------------------------------------------------------------
// KV GEMM via bf16 MFMA: kvbuf[nl][m], grid = 312
// ---------------------------------------------------------------------------
__global__ __launch_bounds__(256) void kvgemm_kernel(
    const unsigned short* __restrict__ tokT,
    const unsigned short* __restrict__ Wkv,
    const float* __restrict__ bkv,
    float* __restrict__ kvbuf)
{
    __shared__ unsigned char Ab[128 * 128];
    __shared__ unsigned char Bb[64 * 128];

    const int blk = blockIdx.x;
    const int mt = blk / 39, nt = blk % 39;
    const int m0 = mt * 128, nl0 = nt * 64;
    const int t = threadIdx.x;
    const int lane = t & 63, w = t >> 6;
    const int wr = w >> 1, wc = w & 1;

    f32x4 acc[4][2];
#pragma unroll
    for (int i = 0; i < 4; ++i)
#pragma unroll
        for (int j = 0; j < 2; ++j) acc[i][j] = (f32x4){0.f, 0.f, 0.f, 0.f};

    for (int c0 = 0; c0 < 512; c0 += 64) {
        __syncthreads();
#pragma unroll
        for (int s = 0; s < 4; ++s) {
            int idx = t + s * 256;
            int row = idx >> 3, k8 = idx & 7;
            bf16x8 v = *(const bf16x8*)&Wkv[(size_t)(m0 + row) * 512 + c0 + k8 * 8];
            *(bf16x8*)(Ab + row * 128 + ((k8 * 16) ^ ((row & 7) << 4))) = v;
        }
#pragma unroll
        for (int s = 0; s < 2; ++s) {
            int idx = t + s * 256;
            int row = idx >> 3, k8 = idx & 7;
            bf16x8 v = *(const bf16x8*)&tokT[(size_t)(nl0 + row) * 512 + c0 + k8 * 8];
            *(bf16x8*)(Bb + row * 128 + ((k8 * 16) ^ ((row & 7) << 4))) = v;
        }
        __syncthreads();

#pragma unroll
        for (int ks = 0; ks < 2; ++ks) {
            const int kb = ks * 64 + (lane >> 4) * 16;
            bf16x8 a[4], b[2];
#pragma unroll
            for (int i = 0; i < 4; ++i) {
                int row = wr * 64 + i * 16 + (lane & 15);
                a[i] = *(const bf16x8*)(Ab + row * 128 + (kb ^ ((row & 7) << 4)));
            }
#pragma unroll
            for (int j = 0; j < 2; ++j) {
                int row = wc * 32 + j * 16 + (lane & 15);
                b[j] = *(const bf16x8*)(Bb + row * 128 + (kb ^ ((row & 7) << 4)));
            }
#pragma unroll
            for (int i = 0; i < 4; ++i)
#pragma unroll
                for (int j = 0; j < 2; ++j)
                    acc[i][j] = __builtin_amdgcn_mfma_f32_16x16x32_bf16(
                        a[i], b[j], acc[i][j], 0, 0, 0);
        }
    }

#pragma unroll
    for (int i = 0; i < 4; ++i) {
        int m = m0 + wr * 64 + i * 16 + (lane >> 4) * 4;
        float4 bias = *(const float4*)&bkv[m];
#pragma unroll
        for (int j = 0; j < 2; ++j) {
            int nl = nl0 + wc * 32 + j * 16 + (lane & 15);
            float4 o;
            o.x = acc[i][j][0] + bias.x;
            o.y = acc[i][j][1] + bias.y;
            o.z = acc[i][j][2] + bias.z;
            o.w = acc[i][j][3] + bias.w;
            *(float4*)&kvbuf[(size_t)nl * 1024 + m] = o;
        }
    }
}

// ---------------------------------------------------------------------------
// Q projection — EXACT R17 (best measured): 128x128 tile, 512 threads /
// 8 waves (2 o-halves x 4 p-quarters, each wave 64o x 32p, acc[4][2]).
// grid = N*32, block 512.
// ---------------------------------------------------------------------------
__global__ __launch_bounds__(512) void qmfma_kernel(
    const float* __restrict__ feature,
    const float* __restrict__ Wq, const float* __restrict__ bq,
    unsigned short* __restrict__ qbuf)
{
    __shared__ unsigned char Ab[128 * 128];
    __shared__ unsigned char Bb[128 * 128];

    const int blk = blockIdx.x;
    const int pt = blk & 7;
    const int ot = (blk >> 3) & 3;
    const int n  = blk >> 5;
    const int o0 = ot * 128, p0 = pt * 128;
    const int t = threadIdx.x;
    const int lane = t & 63, w = t >> 6;    // 8 waves
    const int wr = w >> 2, wc = w & 3;      // 2 x 4 wave grid
    const int q15 = lane & 15, g = lane >> 4;

    f32x4 acc[4][2];
#pragma unroll
    for (int i = 0; i < 4; ++i)
#pragma unroll
        for (int j = 0; j < 2; ++j) acc[i][j] = (f32x4){0.f, 0.f, 0.f, 0.f};

    const float* featn = feature + (size_t)n * C_ * HW_;

    for (int c0 = 0; c0 < C_; c0 += 64) {
        __syncthreads();
        // A-stage: Wq 128 rows x 64 c (f32 -> bf16, swizzled), 4 chunks/thread
#pragma unroll
        for (int s = 0; s < 4; ++s) {
            int idx = t + s * 512;           // 0..2047
            int row = idx >> 4;              // 0..127
            int c4  = (idx & 15) * 4;
            float4 f = *(const float4*)&Wq[(size_t)(o0 + row) * C_ + c0 + c4];
            ushort4 h; h.x = f2bf(f.x); h.y = f2bf(f.y); h.z = f2bf(f.z); h.w = f2bf(f.w);
            *(ushort4*)(Ab + row * 128 + ((c4 * 2) ^ ((row & 7) << 4))) = h;
        }
        // B-stage: feature [c][p] -> Bb[p][c], 4 quarters of c across t>>7
        {
            int p  = t & 127;
            int q2 = t >> 7;                 // 0..3
#pragma unroll
            for (int it = 0; it < 4; ++it) {
                int cl = q2 * 16 + it * 4;
                const float* src = featn + (size_t)(c0 + cl) * HW_ + p0 + p;
                float f0 = src[0];
                float f1 = src[HW_];
                float f2 = src[2 * HW_];
                float f3 = src[3 * HW_];
                ushort4 h; h.x = f2bf(f0); h.y = f2bf(f1); h.z = f2bf(f2); h.w = f2bf(f3);
                *(ushort4*)(Bb + p * 128 + ((cl * 2) ^ ((p & 7) << 4))) = h;
            }
        }
        __syncthreads();

#pragma unroll
        for (int ks = 0; ks < 2; ++ks) {
            const int kb = ks * 64 + g * 16;
            bf16x8 a[4], b[2];
#pragma unroll
            for (int i = 0; i < 4; ++i) {
                int row = wr * 64 + i * 16 + q15;
                a[i] = *(const bf16x8*)(Ab + row * 128 + (kb ^ ((row & 7) << 4)));
            }
#pragma unroll
            for (int j = 0; j < 2; ++j) {
                int prow = wc * 32 + j * 16 + q15;
                b[j] = *(const bf16x8*)(Bb + prow * 128 + (kb ^ ((prow & 7) << 4)));
            }
#pragma unroll
            for (int i = 0; i < 4; ++i)
#pragma unroll
                for (int j = 0; j < 2; ++j)
                    acc[i][j] = __builtin_amdgcn_mfma_f32_16x16x32_bf16(
                        a[i], b[j], acc[i][j], 0, 0, 0);
        }
    }

    // epilogue (measured-fast form): scalar stores to qbuf[n][o][p]
    const float scale = 0.17677669529663687f;  // 1/sqrt(32)
#pragma unroll
    for (int i = 0; i < 4; ++i) {
#pragma unroll
        for (int r = 0; r < 4; ++r) {
            int o = o0 + wr * 64 + i * 16 + (lane >> 4) * 4 + r;
            float bias = bq[o];
#pragma unroll
            for (int j = 0; j < 2; ++j) {
                int p = p0 + wc * 32 + j * 16 + q15;
                qbuf[((size_t)n * C_ + o) * HW_ + p] = f2bf((acc[i][j][r] + bias) * scale);
            }
        }
    }
}

// ---------------------------------------------------------------------------
// Attention via MFMA. grid = N*HEAD*4, block 256.
// ---------------------------------------------------------------------------
__global__ __launch_bounds__(256) void attn_kernel(
    const float* __restrict__ feature,
    const float* __restrict__ kvbuf,
    const unsigned short* __restrict__ qbuf,
    float* __restrict__ out)
{
    __shared__ unsigned char kl[80 * 64];    // K bf16 [l][32d], XOR-swizzled
    __shared__ unsigned char vt[32 * 176];   // V bf16 [d][88l]
    __shared__ unsigned char qs[256 * 64];   // Q bf16 [p][32o], chunk-XOR

    const int blk = blockIdx.x;
    const int pc = blk & 3;
    const int h  = (blk >> 2) & 15;
    const int n  = blk >> 6;
    const int t = threadIdx.x;
    const int lane = t & 63, w = t >> 6;
    const int q15 = lane & 15, g = lane >> 4;
    const int pb = pc * 256;        // block p base
    const int p0 = pb + w * 64;     // wave p base

    // ---- stage Q: qbuf rows [o][p] -> qs[p][o] (chunk-XOR swizzled)
    {
        const unsigned short* qsrc =
            qbuf + ((size_t)n * C_ + h * DH_) * HW_ + pb;
#pragma unroll
        for (int it = 0; it < 4; ++it) {
            int idx = t + it * 256;           // 0..1023
            int oo = idx >> 5;                // 0..31
            int p8 = (idx & 31) * 8;          // 0..248
            bf16x8 v = *(const bf16x8*)(qsrc + (size_t)oo * HW_ + p8);
            int key = ((p8 >> 3) & 3) << 4;   // per-8-row chunk rotation
            int slot = (((oo >> 3) << 4) ^ key) + (oo & 7) * 2;
            union { bf16x8 v8; unsigned short us[8]; } u; u.v8 = v;
#pragma unroll
            for (int j = 0; j < 8; ++j)
                *(unsigned short*)(qs + (p8 + j) * 64 + slot) = u.us[j];
        }
    }

    // zero padding tails
    if (t < 48) *(unsigned int*)(kl + 77 * 64 + t * 4) = 0;   // K rows 77..79
    if (t >= 96 && t < 96 + 352) {                            // V cols 77..87
        int u = t - 96;
        int d = u / 11, l = 77 + u % 11;
        *(unsigned short*)(vt + d * 176 + l * 2) = 0;
    }

    // stage K (swizzled [l][d]) and V (transposed [d][l])
    const float* kvb = kvbuf + (size_t)(n * L_) * 1024 + h * DH_;
    for (int idx = t; idx < L_ * 8; idx += 256) {
        int l = idx >> 3, dq = idx & 7;
        float4 k4 = *(const float4*)&kvb[(size_t)l * 1024 + dq * 4];
        ushort4 hk; hk.x = f2bf(k4.x); hk.y = f2bf(k4.y); hk.z = f2bf(k4.z); hk.w = f2bf(k4.w);
        int cx = dq >> 1, sub = (dq & 1) * 8;
        *(ushort4*)(kl + l * 64 + (((cx ^ (l & 3)) << 4) + sub)) = hk;
        float4 v4 = *(const float4*)&kvb[(size_t)l * 1024 + 512 + dq * 4];
        *(unsigned short*)(vt + (dq * 4 + 0) * 176 + l * 2) = f2bf(v4.x);
        *(unsigned short*)(vt + (dq * 4 + 1) * 176 + l * 2) = f2bf(v4.y);
        *(unsigned short*)(vt + (dq * 4 + 2) * 176 + l * 2) = f2bf(v4.z);
        *(unsigned short*)(vt + (dq * 4 + 3) * 176 + l * 2) = f2bf(v4.w);
    }
    __syncthreads();

    // Q B-frags from qs
    bf16x8 qf[4];
#pragma unroll
    for (int i = 0; i < 4; ++i) {
        int p = w * 64 + i * 16 + q15;
        qf[i] = *(const bf16x8*)(qs + p * 64 + ((g ^ ((p >> 3) & 3)) << 4));
    }
    // K A-frags: row l = lt*16 + q15, k-chunk = g
    bf16x8 kf[5];
#pragma unroll
    for (int lt = 0; lt < 5; ++lt) {
        int l = lt * 16 + q15;
        kf[lt] = *(const bf16x8*)(kl + l * 64 + ((g ^ (l & 3)) << 4));
    }
    // V B-frags (16x16x16): col d = dt*16 + q15, k = lt*16 + g*4 .. +3
    bf16x4 vf[5][2];
#pragma unroll
    for (int lt = 0; lt < 5; ++lt)
#pragma unroll
        for (int dt = 0; dt < 2; ++dt)
            vf[lt][dt] = *(const bf16x4*)(vt + (dt * 16 + q15) * 176 + lt * 32 + g * 8);

    const float* featn = feature + ((size_t)n * C_ + h * DH_) * HW_;
    float* outn = out + ((size_t)n * C_ + h * DH_) * HW_;

#pragma unroll
    for (int i = 0; i < 4; ++i) {
        f32x4 s[5];
#pragma unroll
        for (int lt = 0; lt < 5; ++lt)
            s[lt] = __builtin_amdgcn_mfma_f32_16x16x32_bf16(
                kf[lt], qf[i], (f32x4){0.f, 0.f, 0.f, 0.f}, 0, 0, 0);

#pragma unroll
        for (int r = 0; r < 4; ++r)
            if (4 * g + r >= 13) s[4][r] = -3.0e38f;

        float mx = s[0][0];
#pragma unroll
        for (int lt = 0; lt < 5; ++lt)
#pragma unroll
            for (int r = 0; r < 4; ++r) mx = fmaxf(mx, s[lt][r]);
        mx = fmaxf(mx, __shfl_xor(mx, 16));
        mx = fmaxf(mx, __shfl_xor(mx, 32));

        float Z = 0.f;
#pragma unroll
        for (int lt = 0; lt < 5; ++lt)
#pragma unroll
            for (int r = 0; r < 4; ++r) {
                float e = __expf(s[lt][r] - mx);
                s[lt][r] = e;
                Z += e;
            }
        Z += __shfl_xor(Z, 16);
        Z += __shfl_xor(Z, 32);
        const float inv = 1.f / Z;

        unsigned int pk[5][2];
#pragma unroll
        for (int lt = 0; lt < 5; ++lt) {
            pk[lt][0] = (unsigned int)f2bf(s[lt][0] * inv)
                      | ((unsigned int)f2bf(s[lt][1] * inv) << 16);
            pk[lt][1] = (unsigned int)f2bf(s[lt][2] * inv)
                      | ((unsigned int)f2bf(s[lt][3] * inv) << 16);
        }

        f32x4 pv[2];
        pv[0] = (f32x4){0.f, 0.f, 0.f, 0.f};
        pv[1] = (f32x4){0.f, 0.f, 0.f, 0.f};
#pragma unroll
        for (int lt = 0; lt < 5; ++lt) {
            union { unsigned int u[2]; bf16x4 v; } pa;
            pa.u[0] = pk[lt][0];
            pa.u[1] = pk[lt][1];
#pragma unroll
            for (int dt = 0; dt < 2; ++dt)
                pv[dt] = __builtin_amdgcn_mfma_f32_16x16x16bf16_1k(
                    pa.v, vf[lt][dt], pv[dt], 0, 0, 0);
        }

#pragma unroll
        for (int dt = 0; dt < 2; ++dt) {
            size_t off = (size_t)(dt * 16 + q15) * HW_ + p0 + i * 16 + g * 4;
            float4 f = *(const float4*)&featn[off];
            float4 o;
            o.x = f.x + pv[dt][0];
            o.y = f.y + pv[dt][1];
            o.z = f.z + pv[dt][2];
            o.w = f.w + pv[dt][3];
            *(float4*)&outn[off] = o;
        }
    }
}

// ---------------------------------------------------------------------------
extern "C" void kernel_launch(void* const* d_in, const int* in_sizes, int n_in,
                              void* d_out, int out_size, void* d_ws, size_t ws_size,
                              hipStream_t stream)
{
    const float* feature = (const float*)d_in[0];
    const float* token   = (const float*)d_in[1];
    const float* Wv      = (const float*)d_in[2];
    const float* bv      = (const float*)d_in[3];
    const float* Wk      = (const float*)d_in[4];
    const float* bk      = (const float*)d_in[5];
    const float* Wq      = (const float*)d_in[6];
    const float* bq      = (const float*)d_in[7];
    float* out = (float*)d_out;

    // workspace layout
    float* kvbuf = (float*)d_ws;                                   // NLP_*1024 f32
    unsigned short* tokT = (unsigned short*)(kvbuf + (size_t)NLP_ * 1024);  // NLP_*512 bf16
    unsigned short* Wkv  = tokT + (size_t)NLP_ * 512;              // 1024*512 bf16
    float* bkv = (float*)(Wkv + (size_t)1024 * 512);               // 1024 f32
    unsigned short* qbuf = (unsigned short*)(bkv + 1024);          // N*C*HW bf16 [n][o][p]

    prep_kernel<<<288, 256, 0, stream>>>(token, Wk, bk, Wv, bv, tokT, Wkv, bkv);
    kvgemm_kernel<<<312, 256, 0, stream>>>(tokT, Wkv, bkv, kvbuf);
    qmfma_kernel<<<N_ * 32, 512, 0, stream>>>(feature, Wq, bq, qbuf);
    attn_kernel<<<N_ * HEAD_ * 4, 256, 0, stream>>>(feature, kvbuf, qbuf, out);

    // tuple output: token passthrough
    hipMemcpyAsync(out + (size_t)N_ * C_ * HW_, token,
                   (size_t)N_ * L_ * CT_ * sizeof(float),
                   hipMemcpyDeviceToDevice, stream);
}

// Round 21
// 97.297 us; speedup vs baseline: 1.1611x; 1.0066x over previous
//
#include <hip/hip_runtime.h>
#include <hip/hip_bf16.h>

// Sizes (fixed by the problem)
#define N_   32
#define L_   77
#define CT_  512
#define C_   512
#define HW_  1024
#define HEAD_ 16
#define DH_  32   // C/HEAD
#define NL_  (N_ * L_)     // 2464
#define NLP_ 2496          // padded to 39*64

typedef __attribute__((ext_vector_type(8))) short bf16x8;
typedef __attribute__((ext_vector_type(4))) short bf16x4;
typedef __attribute__((ext_vector_type(4))) float f32x4;

static __device__ __forceinline__ unsigned short f2bf(float f) {
    unsigned int u = __float_as_uint(f);
    unsigned int r = (u + 0x7fffu + ((u >> 16) & 1u)) >> 16;  // RNE
    return (unsigned short)r;
}

// ---------------------------------------------------------------------------
// Prep: token -> tokT[nl][c] bf16, Wk/Wv -> Wkv bf16, bkv. grid = 288
// ---------------------------------------------------------------------------
__global__ __launch_bounds__(256) void prep_kernel(
    const float* __restrict__ token,
    const float* __restrict__ Wk, const float* __restrict__ bk,
    const float* __restrict__ Wv, const float* __restrict__ bv,
    unsigned short* __restrict__ tokT, unsigned short* __restrict__ Wkv,
    float* __restrict__ bkv)
{
    const int blk = blockIdx.x;
    const int t = threadIdx.x;
    if (blk < 256) {
        __shared__ float tile[64][81];
        const int n = blk >> 3, c0 = (blk & 7) * 64;
        const float* src = token + (size_t)n * (CT_ * L_) + (size_t)c0 * L_;
        for (int idx = t; idx < 64 * L_; idx += 256) {
            int cc = idx / L_, l = idx - cc * L_;
            tile[cc][l] = src[idx];
        }
        __syncthreads();
        for (int idx = t; idx < L_ * 16; idx += 256) {
            int l = idx >> 4, cq = (idx & 15) * 4;
            ushort4 h;
            h.x = f2bf(tile[cq + 0][l]);
            h.y = f2bf(tile[cq + 1][l]);
            h.z = f2bf(tile[cq + 2][l]);
            h.w = f2bf(tile[cq + 3][l]);
            *(ushort4*)&tokT[((size_t)(n * L_ + l)) * 512 + c0 + cq] = h;
        }
    } else {
        const int wb = blk - 256;
        const int m0 = wb * 32;
        for (int idx = t; idx < 32 * 128; idx += 256) {
            int mr = idx >> 7, c4 = (idx & 127) * 4;
            int m = m0 + mr;
            const float* src = (m < 512) ? (Wk + (size_t)m * 512 + c4)
                                         : (Wv + (size_t)(m - 512) * 512 + c4);
            float4 f = *(const float4*)src;
            ushort4 h; h.x = f2bf(f.x); h.y = f2bf(f.y); h.z = f2bf(f.z); h.w = f2bf(f.w);
            *(ushort4*)&Wkv[(size_t)m * 512 + c4] = h;
        }
        if (wb == 0) {
            for (int idx = t; idx < 1024; idx += 256)
                bkv[idx] = (idx < 512) ? bk[idx] : bv[idx - 512];
        }
    }
}

// ---------------------------------------------------------------------------
// KV GEMM via bf16 MFMA (EXACT R20): kvbuf[nl][m], grid = 312
// ---------------------------------------------------------------------------
__global__ __launch_bounds__(256) void kvgemm_kernel(
    const unsigned short* __restrict__ tokT,
    const unsigned short* __restrict__ Wkv,
    const float* __restrict__ bkv,
    float* __restrict__ kvbuf)
{
    __shared__ unsigned char Ab[128 * 128];
    __shared__ unsigned char Bb[64 * 128];

    const int blk = blockIdx.x;
    const int mt = blk / 39, nt = blk % 39;
    const int m0 = mt * 128, nl0 = nt * 64;
    const int t = threadIdx.x;
    const int lane = t & 63, w = t >> 6;
    const int wr = w >> 1, wc = w & 1;

    f32x4 acc[4][2];
#pragma unroll
    for (int i = 0; i < 4; ++i)
#pragma unroll
        for (int j = 0; j < 2; ++j) acc[i][j] = (f32x4){0.f, 0.f, 0.f, 0.f};

    for (int c0 = 0; c0 < 512; c0 += 64) {
        __syncthreads();
#pragma unroll
        for (int s = 0; s < 4; ++s) {
            int idx = t + s * 256;
            int row = idx >> 3, k8 = idx & 7;
            bf16x8 v = *(const bf16x8*)&Wkv[(size_t)(m0 + row) * 512 + c0 + k8 * 8];
            *(bf16x8*)(Ab + row * 128 + ((k8 * 16) ^ ((row & 7) << 4))) = v;
        }
#pragma unroll
        for (int s = 0; s < 2; ++s) {
            int idx = t + s * 256;
            int row = idx >> 3, k8 = idx & 7;
            bf16x8 v = *(const bf16x8*)&tokT[(size_t)(nl0 + row) * 512 + c0 + k8 * 8];
            *(bf16x8*)(Bb + row * 128 + ((k8 * 16) ^ ((row & 7) << 4))) = v;
        }
        __syncthreads();

#pragma unroll
        for (int ks = 0; ks < 2; ++ks) {
            const int kb = ks * 64 + (lane >> 4) * 16;
            bf16x8 a[4], b[2];
#pragma unroll
            for (int i = 0; i < 4; ++i) {
                int row = wr * 64 + i * 16 + (lane & 15);
                a[i] = *(const bf16x8*)(Ab + row * 128 + (kb ^ ((row & 7) << 4)));
            }
#pragma unroll
            for (int j = 0; j < 2; ++j) {
                int row = wc * 32 + j * 16 + (lane & 15);
                b[j] = *(const bf16x8*)(Bb + row * 128 + (kb ^ ((row & 7) << 4)));
            }
#pragma unroll
            for (int i = 0; i < 4; ++i)
#pragma unroll
                for (int j = 0; j < 2; ++j)
                    acc[i][j] = __builtin_amdgcn_mfma_f32_16x16x32_bf16(
                        a[i], b[j], acc[i][j], 0, 0, 0);
        }
    }

#pragma unroll
    for (int i = 0; i < 4; ++i) {
        int m = m0 + wr * 64 + i * 16 + (lane >> 4) * 4;
        float4 bias = *(const float4*)&bkv[m];
#pragma unroll
        for (int j = 0; j < 2; ++j) {
            int nl = nl0 + wc * 32 + j * 16 + (lane & 15);
            float4 o;
            o.x = acc[i][j][0] + bias.x;
            o.y = acc[i][j][1] + bias.y;
            o.z = acc[i][j][2] + bias.z;
            o.w = acc[i][j][3] + bias.w;
            *(float4*)&kvbuf[(size_t)nl * 1024 + m] = o;
        }
    }
}

// ---------------------------------------------------------------------------
// Q projection — R17/R20 geometry + T14 async-STAGE split: next step's
// global loads issued after the LDS write, before the MFMA barrier, so the
// load latency hides under MFMA. 128x128 tile, 512 threads / 8 waves.
// grid = N*32, block 512.
// ---------------------------------------------------------------------------
__global__ __launch_bounds__(512) void qmfma_kernel(
    const float* __restrict__ feature,
    const float* __restrict__ Wq, const float* __restrict__ bq,
    unsigned short* __restrict__ qbuf)
{
    __shared__ unsigned char Ab[128 * 128];
    __shared__ unsigned char Bb[128 * 128];

    const int blk = blockIdx.x;
    const int pt = blk & 7;
    const int ot = (blk >> 3) & 3;
    const int n  = blk >> 5;
    const int o0 = ot * 128, p0 = pt * 128;
    const int t = threadIdx.x;
    const int lane = t & 63, w = t >> 6;    // 8 waves
    const int wr = w >> 2, wc = w & 3;      // 2 x 4 wave grid
    const int q15 = lane & 15, g = lane >> 4;

    f32x4 acc[4][2];
#pragma unroll
    for (int i = 0; i < 4; ++i)
#pragma unroll
        for (int j = 0; j < 2; ++j) acc[i][j] = (f32x4){0.f, 0.f, 0.f, 0.f};

    const float* featn = feature + (size_t)n * C_ * HW_;
    const int pB  = t & 127;        // B-stage p index
    const int q2B = t >> 7;         // B-stage c-quarter

    // prologue: load step-0 A/B into registers
    float4 ra[4], rb[4];
#pragma unroll
    for (int s = 0; s < 4; ++s) {
        int idx = t + s * 512;
        int row = idx >> 4, c4 = (idx & 15) * 4;
        ra[s] = *(const float4*)&Wq[(size_t)(o0 + row) * C_ + c4];
    }
#pragma unroll
    for (int it = 0; it < 4; ++it) {
        int cl = q2B * 16 + it * 4;
        const float* src = featn + (size_t)cl * HW_ + p0 + pB;
        rb[it].x = src[0];
        rb[it].y = src[HW_];
        rb[it].z = src[2 * HW_];
        rb[it].w = src[3 * HW_];
    }

    for (int c0 = 0; c0 < C_; c0 += 64) {
        __syncthreads();   // previous iteration's LDS reads complete
        // write current registers -> LDS (convert here)
#pragma unroll
        for (int s = 0; s < 4; ++s) {
            int idx = t + s * 512;
            int row = idx >> 4, c4 = (idx & 15) * 4;
            ushort4 h;
            h.x = f2bf(ra[s].x); h.y = f2bf(ra[s].y);
            h.z = f2bf(ra[s].z); h.w = f2bf(ra[s].w);
            *(ushort4*)(Ab + row * 128 + ((c4 * 2) ^ ((row & 7) << 4))) = h;
        }
#pragma unroll
        for (int it = 0; it < 4; ++it) {
            int cl = q2B * 16 + it * 4;
            ushort4 h;
            h.x = f2bf(rb[it].x); h.y = f2bf(rb[it].y);
            h.z = f2bf(rb[it].z); h.w = f2bf(rb[it].w);
            *(ushort4*)(Bb + pB * 128 + ((cl * 2) ^ ((pB & 7) << 4))) = h;
        }
        // issue NEXT step's loads (consumed next iteration -> hidden latency)
        if (c0 + 64 < C_) {
#pragma unroll
            for (int s = 0; s < 4; ++s) {
                int idx = t + s * 512;
                int row = idx >> 4, c4 = (idx & 15) * 4;
                ra[s] = *(const float4*)&Wq[(size_t)(o0 + row) * C_ + c0 + 64 + c4];
            }
#pragma unroll
            for (int it = 0; it < 4; ++it) {
                int cl = q2B * 16 + it * 4;
                const float* src = featn + (size_t)(c0 + 64 + cl) * HW_ + p0 + pB;
                rb[it].x = src[0];
                rb[it].y = src[HW_];
                rb[it].z = src[2 * HW_];
                rb[it].w = src[3 * HW_];
            }
        }
        __syncthreads();   // LDS writes visible

#pragma unroll
        for (int ks = 0; ks < 2; ++ks) {
            const int kb = ks * 64 + g * 16;
            bf16x8 a[4], b[2];
#pragma unroll
            for (int i = 0; i < 4; ++i) {
                int row = wr * 64 + i * 16 + q15;
                a[i] = *(const bf16x8*)(Ab + row * 128 + (kb ^ ((row & 7) << 4)));
            }
#pragma unroll
            for (int j = 0; j < 2; ++j) {
                int prow = wc * 32 + j * 16 + q15;
                b[j] = *(const bf16x8*)(Bb + prow * 128 + (kb ^ ((prow & 7) << 4)));
            }
#pragma unroll
            for (int i = 0; i < 4; ++i)
#pragma unroll
                for (int j = 0; j < 2; ++j)
                    acc[i][j] = __builtin_amdgcn_mfma_f32_16x16x32_bf16(
                        a[i], b[j], acc[i][j], 0, 0, 0);
        }
    }

    // epilogue (measured-fast form): scalar stores to qbuf[n][o][p]
    const float scale = 0.17677669529663687f;  // 1/sqrt(32)
#pragma unroll
    for (int i = 0; i < 4; ++i) {
#pragma unroll
        for (int r = 0; r < 4; ++r) {
            int o = o0 + wr * 64 + i * 16 + (lane >> 4) * 4 + r;
            float bias = bq[o];
#pragma unroll
            for (int j = 0; j < 2; ++j) {
                int p = p0 + wc * 32 + j * 16 + q15;
                qbuf[((size_t)n * C_ + o) * HW_ + p] = f2bf((acc[i][j][r] + bias) * scale);
            }
        }
    }
}

// ---------------------------------------------------------------------------
// Attention via MFMA (EXACT R20). grid = N*HEAD*4, block 256.
// ---------------------------------------------------------------------------
__global__ __launch_bounds__(256) void attn_kernel(
    const float* __restrict__ feature,
    const float* __restrict__ kvbuf,
    const unsigned short* __restrict__ qbuf,
    float* __restrict__ out)
{
    __shared__ unsigned char kl[80 * 64];    // K bf16 [l][32d], XOR-swizzled
    __shared__ unsigned char vt[32 * 176];   // V bf16 [d][88l]
    __shared__ unsigned char qs[256 * 64];   // Q bf16 [p][32o], chunk-XOR

    const int blk = blockIdx.x;
    const int pc = blk & 3;
    const int h  = (blk >> 2) & 15;
    const int n  = blk >> 6;
    const int t = threadIdx.x;
    const int lane = t & 63, w = t >> 6;
    const int q15 = lane & 15, g = lane >> 4;
    const int pb = pc * 256;        // block p base
    const int p0 = pb + w * 64;     // wave p base

    // ---- stage Q: qbuf rows [o][p] -> qs[p][o] (chunk-XOR swizzled)
    {
        const unsigned short* qsrc =
            qbuf + ((size_t)n * C_ + h * DH_) * HW_ + pb;
#pragma unroll
        for (int it = 0; it < 4; ++it) {
            int idx = t + it * 256;           // 0..1023
            int oo = idx >> 5;                // 0..31
            int p8 = (idx & 31) * 8;          // 0..248
            bf16x8 v = *(const bf16x8*)(qsrc + (size_t)oo * HW_ + p8);
            int key = ((p8 >> 3) & 3) << 4;   // per-8-row chunk rotation
            int slot = (((oo >> 3) << 4) ^ key) + (oo & 7) * 2;
            union { bf16x8 v8; unsigned short us[8]; } u; u.v8 = v;
#pragma unroll
            for (int j = 0; j < 8; ++j)
                *(unsigned short*)(qs + (p8 + j) * 64 + slot) = u.us[j];
        }
    }

    // zero padding tails
    if (t < 48) *(unsigned int*)(kl + 77 * 64 + t * 4) = 0;   // K rows 77..79
    if (t >= 96 && t < 96 + 352) {                            // V cols 77..87
        int u = t - 96;
        int d = u / 11, l = 77 + u % 11;
        *(unsigned short*)(vt + d * 176 + l * 2) = 0;
    }

    // stage K (swizzled [l][d]) and V (transposed [d][l])
    const float* kvb = kvbuf + (size_t)(n * L_) * 1024 + h * DH_;
    for (int idx = t; idx < L_ * 8; idx += 256) {
        int l = idx >> 3, dq = idx & 7;
        float4 k4 = *(const float4*)&kvb[(size_t)l * 1024 + dq * 4];
        ushort4 hk; hk.x = f2bf(k4.x); hk.y = f2bf(k4.y); hk.z = f2bf(k4.z); hk.w = f2bf(k4.w);
        int cx = dq >> 1, sub = (dq & 1) * 8;
        *(ushort4*)(kl + l * 64 + (((cx ^ (l & 3)) << 4) + sub)) = hk;
        float4 v4 = *(const float4*)&kvb[(size_t)l * 1024 + 512 + dq * 4];
        *(unsigned short*)(vt + (dq * 4 + 0) * 176 + l * 2) = f2bf(v4.x);
        *(unsigned short*)(vt + (dq * 4 + 1) * 176 + l * 2) = f2bf(v4.y);
        *(unsigned short*)(vt + (dq * 4 + 2) * 176 + l * 2) = f2bf(v4.z);
        *(unsigned short*)(vt + (dq * 4 + 3) * 176 + l * 2) = f2bf(v4.w);
    }
    __syncthreads();

    // Q B-frags from qs
    bf16x8 qf[4];
#pragma unroll
    for (int i = 0; i < 4; ++i) {
        int p = w * 64 + i * 16 + q15;
        qf[i] = *(const bf16x8*)(qs + p * 64 + ((g ^ ((p >> 3) & 3)) << 4));
    }
    // K A-frags: row l = lt*16 + q15, k-chunk = g
    bf16x8 kf[5];
#pragma unroll
    for (int lt = 0; lt < 5; ++lt) {
        int l = lt * 16 + q15;
        kf[lt] = *(const bf16x8*)(kl + l * 64 + ((g ^ (l & 3)) << 4));
    }
    // V B-frags (16x16x16): col d = dt*16 + q15, k = lt*16 + g*4 .. +3
    bf16x4 vf[5][2];
#pragma unroll
    for (int lt = 0; lt < 5; ++lt)
#pragma unroll
        for (int dt = 0; dt < 2; ++dt)
            vf[lt][dt] = *(const bf16x4*)(vt + (dt * 16 + q15) * 176 + lt * 32 + g * 8);

    const float* featn = feature + ((size_t)n * C_ + h * DH_) * HW_;
    float* outn = out + ((size_t)n * C_ + h * DH_) * HW_;

#pragma unroll
    for (int i = 0; i < 4; ++i) {
        f32x4 s[5];
#pragma unroll
        for (int lt = 0; lt < 5; ++lt)
            s[lt] = __builtin_amdgcn_mfma_f32_16x16x32_bf16(
                kf[lt], qf[i], (f32x4){0.f, 0.f, 0.f, 0.f}, 0, 0, 0);

#pragma unroll
        for (int r = 0; r < 4; ++r)
            if (4 * g + r >= 13) s[4][r] = -3.0e38f;

        float mx = s[0][0];
#pragma unroll
        for (int lt = 0; lt < 5; ++lt)
#pragma unroll
            for (int r = 0; r < 4; ++r) mx = fmaxf(mx, s[lt][r]);
        mx = fmaxf(mx, __shfl_xor(mx, 16));
        mx = fmaxf(mx, __shfl_xor(mx, 32));

        float Z = 0.f;
#pragma unroll
        for (int lt = 0; lt < 5; ++lt)
#pragma unroll
            for (int r = 0; r < 4; ++r) {
                float e = __expf(s[lt][r] - mx);
                s[lt][r] = e;
                Z += e;
            }
        Z += __shfl_xor(Z, 16);
        Z += __shfl_xor(Z, 32);
        const float inv = 1.f / Z;

        unsigned int pk[5][2];
#pragma unroll
        for (int lt = 0; lt < 5; ++lt) {
            pk[lt][0] = (unsigned int)f2bf(s[lt][0] * inv)
                      | ((unsigned int)f2bf(s[lt][1] * inv) << 16);
            pk[lt][1] = (unsigned int)f2bf(s[lt][2] * inv)
                      | ((unsigned int)f2bf(s[lt][3] * inv) << 16);
        }

        f32x4 pv[2];
        pv[0] = (f32x4){0.f, 0.f, 0.f, 0.f};
        pv[1] = (f32x4){0.f, 0.f, 0.f, 0.f};
#pragma unroll
        for (int lt = 0; lt < 5; ++lt) {
            union { unsigned int u[2]; bf16x4 v; } pa;
            pa.u[0] = pk[lt][0];
            pa.u[1] = pk[lt][1];
#pragma unroll
            for (int dt = 0; dt < 2; ++dt)
                pv[dt] = __builtin_amdgcn_mfma_f32_16x16x16bf16_1k(
                    pa.v, vf[lt][dt], pv[dt], 0, 0, 0);
        }

#pragma unroll
        for (int dt = 0; dt < 2; ++dt) {
            size_t off = (size_t)(dt * 16 + q15) * HW_ + p0 + i * 16 + g * 4;
            float4 f = *(const float4*)&featn[off];
            float4 o;
            o.x = f.x + pv[dt][0];
            o.y = f.y + pv[dt][1];
            o.z = f.z + pv[dt][2];
            o.w = f.w + pv[dt][3];
            *(float4*)&outn[off] = o;
        }
    }
}

// ---------------------------------------------------------------------------
extern "C" void kernel_launch(void* const* d_in, const int* in_sizes, int n_in,
                              void* d_out, int out_size, void* d_ws, size_t ws_size,
                              hipStream_t stream)
{
    const float* feature = (const float*)d_in[0];
    const float* token   = (const float*)d_in[1];
    const float* Wv      = (const float*)d_in[2];
    const float* bv      = (const float*)d_in[3];
    const float* Wk      = (const float*)d_in[4];
    const float* bk      = (const float*)d_in[5];
    const float* Wq      = (const float*)d_in[6];
    const float* bq      = (const float*)d_in[7];
    float* out = (float*)d_out;

    // workspace layout
    float* kvbuf = (float*)d_ws;                                   // NLP_*1024 f32
    unsigned short* tokT = (unsigned short*)(kvbuf + (size_t)NLP_ * 1024);  // NLP_*512 bf16
    unsigned short* Wkv  = tokT + (size_t)NLP_ * 512;              // 1024*512 bf16
    float* bkv = (float*)(Wkv + (size_t)1024 * 512);               // 1024 f32
    unsigned short* qbuf = (unsigned short*)(bkv + 1024);          // N*C*HW bf16 [n][o][p]

    prep_kernel<<<288, 256, 0, stream>>>(token, Wk, bk, Wv, bv, tokT, Wkv, bkv);
    kvgemm_kernel<<<312, 256, 0, stream>>>(tokT, Wkv, bkv, kvbuf);
    qmfma_kernel<<<N_ * 32, 512, 0, stream>>>(feature, Wq, bq, qbuf);
    attn_kernel<<<N_ * HEAD_ * 4, 256, 0, stream>>>(feature, kvbuf, qbuf, out);

    // tuple output: token passthrough
    hipMemcpyAsync(out + (size_t)N_ * C_ * HW_, token,
                   (size_t)N_ * L_ * CT_ * sizeof(float),
                   hipMemcpyDeviceToDevice, stream);
}

// Round 22
// 97.059 us; speedup vs baseline: 1.1639x; 1.0025x over previous
//
#include <hip/hip_runtime.h>
#include <hip/hip_bf16.h>

// Sizes (fixed by the problem)
#define N_   32
#define L_   77
#define CT_  512
#define C_   512
#define HW_  1024
#define HEAD_ 16
#define DH_  32   // C/HEAD
#define NL_  (N_ * L_)     // 2464
#define NLP_ 2496          // padded to 39*64

typedef __attribute__((ext_vector_type(8))) short bf16x8;
typedef __attribute__((ext_vector_type(4))) short bf16x4;
typedef __attribute__((ext_vector_type(4))) float f32x4;

static __device__ __forceinline__ unsigned short f2bf(float f) {
    unsigned int u = __float_as_uint(f);
    unsigned int r = (u + 0x7fffu + ((u >> 16) & 1u)) >> 16;  // RNE
    return (unsigned short)r;
}

// ---------------------------------------------------------------------------
// Prep: token -> tokT[nl][c] bf16, Wk/Wv -> Wkv bf16, bkv. grid = 288
// ---------------------------------------------------------------------------
__global__ __launch_bounds__(256) void prep_kernel(
    const float* __restrict__ token,
    const float* __restrict__ Wk, const float* __restrict__ bk,
    const float* __restrict__ Wv, const float* __restrict__ bv,
    unsigned short* __restrict__ tokT, unsigned short* __restrict__ Wkv,
    float* __restrict__ bkv)
{
    const int blk = blockIdx.x;
    const int t = threadIdx.x;
    if (blk < 256) {
        __shared__ float tile[64][81];
        const int n = blk >> 3, c0 = (blk & 7) * 64;
        const float* src = token + (size_t)n * (CT_ * L_) + (size_t)c0 * L_;
        for (int idx = t; idx < 64 * L_; idx += 256) {
            int cc = idx / L_, l = idx - cc * L_;
            tile[cc][l] = src[idx];
        }
        __syncthreads();
        for (int idx = t; idx < L_ * 16; idx += 256) {
            int l = idx >> 4, cq = (idx & 15) * 4;
            ushort4 h;
            h.x = f2bf(tile[cq + 0][l]);
            h.y = f2bf(tile[cq + 1][l]);
            h.z = f2bf(tile[cq + 2][l]);
            h.w = f2bf(tile[cq + 3][l]);
            *(ushort4*)&tokT[((size_t)(n * L_ + l)) * 512 + c0 + cq] = h;
        }
    } else {
        const int wb = blk - 256;
        const int m0 = wb * 32;
        for (int idx = t; idx < 32 * 128; idx += 256) {
            int mr = idx >> 7, c4 = (idx & 127) * 4;
            int m = m0 + mr;
            const float* src = (m < 512) ? (Wk + (size_t)m * 512 + c4)
                                         : (Wv + (size_t)(m - 512) * 512 + c4);
            float4 f = *(const float4*)src;
            ushort4 h; h.x = f2bf(f.x); h.y = f2bf(f.y); h.z = f2bf(f.z); h.w = f2bf(f.w);
            *(ushort4*)&Wkv[(size_t)m * 512 + c4] = h;
        }
        if (wb == 0) {
            for (int idx = t; idx < 1024; idx += 256)
                bkv[idx] = (idx < 512) ? bk[idx] : bv[idx - 512];
        }
    }
}

// ---------------------------------------------------------------------------
// KV GEMM via bf16 MFMA: kvbuf[nl][m], grid = 312
// ---------------------------------------------------------------------------
__global__ __launch_bounds__(256) void kvgemm_kernel(
    const unsigned short* __restrict__ tokT,
    const unsigned short* __restrict__ Wkv,
    const float* __restrict__ bkv,
    float* __restrict__ kvbuf)
{
    __shared__ unsigned char Ab[128 * 128];
    __shared__ unsigned char Bb[64 * 128];

    const int blk = blockIdx.x;
    const int mt = blk / 39, nt = blk % 39;
    const int m0 = mt * 128, nl0 = nt * 64;
    const int t = threadIdx.x;
    const int lane = t & 63, w = t >> 6;
    const int wr = w >> 1, wc = w & 1;

    f32x4 acc[4][2];
#pragma unroll
    for (int i = 0; i < 4; ++i)
#pragma unroll
        for (int j = 0; j < 2; ++j) acc[i][j] = (f32x4){0.f, 0.f, 0.f, 0.f};

    for (int c0 = 0; c0 < 512; c0 += 64) {
        __syncthreads();
#pragma unroll
        for (int s = 0; s < 4; ++s) {
            int idx = t + s * 256;
            int row = idx >> 3, k8 = idx & 7;
            bf16x8 v = *(const bf16x8*)&Wkv[(size_t)(m0 + row) * 512 + c0 + k8 * 8];
            *(bf16x8*)(Ab + row * 128 + ((k8 * 16) ^ ((row & 7) << 4))) = v;
        }
#pragma unroll
        for (int s = 0; s < 2; ++s) {
            int idx = t + s * 256;
            int row = idx >> 3, k8 = idx & 7;
            bf16x8 v = *(const bf16x8*)&tokT[(size_t)(nl0 + row) * 512 + c0 + k8 * 8];
            *(bf16x8*)(Bb + row * 128 + ((k8 * 16) ^ ((row & 7) << 4))) = v;
        }
        __syncthreads();

#pragma unroll
        for (int ks = 0; ks < 2; ++ks) {
            const int kb = ks * 64 + (lane >> 4) * 16;
            bf16x8 a[4], b[2];
#pragma unroll
            for (int i = 0; i < 4; ++i) {
                int row = wr * 64 + i * 16 + (lane & 15);
                a[i] = *(const bf16x8*)(Ab + row * 128 + (kb ^ ((row & 7) << 4)));
            }
#pragma unroll
            for (int j = 0; j < 2; ++j) {
                int row = wc * 32 + j * 16 + (lane & 15);
                b[j] = *(const bf16x8*)(Bb + row * 128 + (kb ^ ((row & 7) << 4)));
            }
#pragma unroll
            for (int i = 0; i < 4; ++i)
#pragma unroll
                for (int j = 0; j < 2; ++j)
                    acc[i][j] = __builtin_amdgcn_mfma_f32_16x16x32_bf16(
                        a[i], b[j], acc[i][j], 0, 0, 0);
        }
    }

#pragma unroll
    for (int i = 0; i < 4; ++i) {
        int m = m0 + wr * 64 + i * 16 + (lane >> 4) * 4;
        float4 bias = *(const float4*)&bkv[m];
#pragma unroll
        for (int j = 0; j < 2; ++j) {
            int nl = nl0 + wc * 32 + j * 16 + (lane & 15);
            float4 o;
            o.x = acc[i][j][0] + bias.x;
            o.y = acc[i][j][1] + bias.y;
            o.z = acc[i][j][2] + bias.z;
            o.w = acc[i][j][3] + bias.w;
            *(float4*)&kvbuf[(size_t)nl * 1024 + m] = o;
        }
    }
}

// ---------------------------------------------------------------------------
// Q projection — best measured (R17/R20): 128x128 tile, 512 threads /
// 8 waves (2 o-halves x 4 p-quarters, each wave 64o x 32p, acc[4][2]).
// grid = N*32, block 512.
// ---------------------------------------------------------------------------
__global__ __launch_bounds__(512) void qmfma_kernel(
    const float* __restrict__ feature,
    const float* __restrict__ Wq, const float* __restrict__ bq,
    unsigned short* __restrict__ qbuf)
{
    __shared__ unsigned char Ab[128 * 128];
    __shared__ unsigned char Bb[128 * 128];

    const int blk = blockIdx.x;
    const int pt = blk & 7;
    const int ot = (blk >> 3) & 3;
    const int n  = blk >> 5;
    const int o0 = ot * 128, p0 = pt * 128;
    const int t = threadIdx.x;
    const int lane = t & 63, w = t >> 6;    // 8 waves
    const int wr = w >> 2, wc = w & 3;      // 2 x 4 wave grid
    const int q15 = lane & 15, g = lane >> 4;

    f32x4 acc[4][2];
#pragma unroll
    for (int i = 0; i < 4; ++i)
#pragma unroll
        for (int j = 0; j < 2; ++j) acc[i][j] = (f32x4){0.f, 0.f, 0.f, 0.f};

    const float* featn = feature + (size_t)n * C_ * HW_;

    for (int c0 = 0; c0 < C_; c0 += 64) {
        __syncthreads();
        // A-stage: Wq 128 rows x 64 c (f32 -> bf16, swizzled), 4 chunks/thread
#pragma unroll
        for (int s = 0; s < 4; ++s) {
            int idx = t + s * 512;           // 0..2047
            int row = idx >> 4;              // 0..127
            int c4  = (idx & 15) * 4;
            float4 f = *(const float4*)&Wq[(size_t)(o0 + row) * C_ + c0 + c4];
            ushort4 h; h.x = f2bf(f.x); h.y = f2bf(f.y); h.z = f2bf(f.z); h.w = f2bf(f.w);
            *(ushort4*)(Ab + row * 128 + ((c4 * 2) ^ ((row & 7) << 4))) = h;
        }
        // B-stage: feature [c][p] -> Bb[p][c], 4 quarters of c across t>>7
        {
            int p  = t & 127;
            int q2 = t >> 7;                 // 0..3
#pragma unroll
            for (int it = 0; it < 4; ++it) {
                int cl = q2 * 16 + it * 4;
                const float* src = featn + (size_t)(c0 + cl) * HW_ + p0 + p;
                float f0 = src[0];
                float f1 = src[HW_];
                float f2 = src[2 * HW_];
                float f3 = src[3 * HW_];
                ushort4 h; h.x = f2bf(f0); h.y = f2bf(f1); h.z = f2bf(f2); h.w = f2bf(f3);
                *(ushort4*)(Bb + p * 128 + ((cl * 2) ^ ((p & 7) << 4))) = h;
            }
        }
        __syncthreads();

#pragma unroll
        for (int ks = 0; ks < 2; ++ks) {
            const int kb = ks * 64 + g * 16;
            bf16x8 a[4], b[2];
#pragma unroll
            for (int i = 0; i < 4; ++i) {
                int row = wr * 64 + i * 16 + q15;
                a[i] = *(const bf16x8*)(Ab + row * 128 + (kb ^ ((row & 7) << 4)));
            }
#pragma unroll
            for (int j = 0; j < 2; ++j) {
                int prow = wc * 32 + j * 16 + q15;
                b[j] = *(const bf16x8*)(Bb + prow * 128 + (kb ^ ((prow & 7) << 4)));
            }
#pragma unroll
            for (int i = 0; i < 4; ++i)
#pragma unroll
                for (int j = 0; j < 2; ++j)
                    acc[i][j] = __builtin_amdgcn_mfma_f32_16x16x32_bf16(
                        a[i], b[j], acc[i][j], 0, 0, 0);
        }
    }

    // epilogue (measured-fast form): scalar stores to qbuf[n][o][p]
    const float scale = 0.17677669529663687f;  // 1/sqrt(32)
#pragma unroll
    for (int i = 0; i < 4; ++i) {
#pragma unroll
        for (int r = 0; r < 4; ++r) {
            int o = o0 + wr * 64 + i * 16 + (lane >> 4) * 4 + r;
            float bias = bq[o];
#pragma unroll
            for (int j = 0; j < 2; ++j) {
                int p = p0 + wc * 32 + j * 16 + q15;
                qbuf[((size_t)n * C_ + o) * HW_ + p] = f2bf((acc[i][j][r] + bias) * scale);
            }
        }
    }
}

// ---------------------------------------------------------------------------
// Attention via MFMA. grid = N*HEAD*4, block 256.
// ---------------------------------------------------------------------------
__global__ __launch_bounds__(256) void attn_kernel(
    const float* __restrict__ feature,
    const float* __restrict__ kvbuf,
    const unsigned short* __restrict__ qbuf,
    float* __restrict__ out)
{
    __shared__ unsigned char kl[80 * 64];    // K bf16 [l][32d], XOR-swizzled
    __shared__ unsigned char vt[32 * 176];   // V bf16 [d][88l]
    __shared__ unsigned char qs[256 * 64];   // Q bf16 [p][32o], chunk-XOR

    const int blk = blockIdx.x;
    const int pc = blk & 3;
    const int h  = (blk >> 2) & 15;
    const int n  = blk >> 6;
    const int t = threadIdx.x;
    const int lane = t & 63, w = t >> 6;
    const int q15 = lane & 15, g = lane >> 4;
    const int pb = pc * 256;        // block p base
    const int p0 = pb + w * 64;     // wave p base

    // ---- stage Q: qbuf rows [o][p] -> qs[p][o] (chunk-XOR swizzled)
    {
        const unsigned short* qsrc =
            qbuf + ((size_t)n * C_ + h * DH_) * HW_ + pb;
#pragma unroll
        for (int it = 0; it < 4; ++it) {
            int idx = t + it * 256;           // 0..1023
            int oo = idx >> 5;                // 0..31
            int p8 = (idx & 31) * 8;          // 0..248
            bf16x8 v = *(const bf16x8*)(qsrc + (size_t)oo * HW_ + p8);
            int key = ((p8 >> 3) & 3) << 4;   // per-8-row chunk rotation
            int slot = (((oo >> 3) << 4) ^ key) + (oo & 7) * 2;
            union { bf16x8 v8; unsigned short us[8]; } u; u.v8 = v;
#pragma unroll
            for (int j = 0; j < 8; ++j)
                *(unsigned short*)(qs + (p8 + j) * 64 + slot) = u.us[j];
        }
    }

    // zero padding tails
    if (t < 48) *(unsigned int*)(kl + 77 * 64 + t * 4) = 0;   // K rows 77..79
    if (t >= 96 && t < 96 + 352) {                            // V cols 77..87
        int u = t - 96;
        int d = u / 11, l = 77 + u % 11;
        *(unsigned short*)(vt + d * 176 + l * 2) = 0;
    }

    // stage K (swizzled [l][d]) and V (transposed [d][l])
    const float* kvb = kvbuf + (size_t)(n * L_) * 1024 + h * DH_;
    for (int idx = t; idx < L_ * 8; idx += 256) {
        int l = idx >> 3, dq = idx & 7;
        float4 k4 = *(const float4*)&kvb[(size_t)l * 1024 + dq * 4];
        ushort4 hk; hk.x = f2bf(k4.x); hk.y = f2bf(k4.y); hk.z = f2bf(k4.z); hk.w = f2bf(k4.w);
        int cx = dq >> 1, sub = (dq & 1) * 8;
        *(ushort4*)(kl + l * 64 + (((cx ^ (l & 3)) << 4) + sub)) = hk;
        float4 v4 = *(const float4*)&kvb[(size_t)l * 1024 + 512 + dq * 4];
        *(unsigned short*)(vt + (dq * 4 + 0) * 176 + l * 2) = f2bf(v4.x);
        *(unsigned short*)(vt + (dq * 4 + 1) * 176 + l * 2) = f2bf(v4.y);
        *(unsigned short*)(vt + (dq * 4 + 2) * 176 + l * 2) = f2bf(v4.z);
        *(unsigned short*)(vt + (dq * 4 + 3) * 176 + l * 2) = f2bf(v4.w);
    }
    __syncthreads();

    // Q B-frags from qs
    bf16x8 qf[4];
#pragma unroll
    for (int i = 0; i < 4; ++i) {
        int p = w * 64 + i * 16 + q15;
        qf[i] = *(const bf16x8*)(qs + p * 64 + ((g ^ ((p >> 3) & 3)) << 4));
    }
    // K A-frags: row l = lt*16 + q15, k-chunk = g
    bf16x8 kf[5];
#pragma unroll
    for (int lt = 0; lt < 5; ++lt) {
        int l = lt * 16 + q15;
        kf[lt] = *(const bf16x8*)(kl + l * 64 + ((g ^ (l & 3)) << 4));
    }
    // V B-frags (16x16x16): col d = dt*16 + q15, k = lt*16 + g*4 .. +3
    bf16x4 vf[5][2];
#pragma unroll
    for (int lt = 0; lt < 5; ++lt)
#pragma unroll
        for (int dt = 0; dt < 2; ++dt)
            vf[lt][dt] = *(const bf16x4*)(vt + (dt * 16 + q15) * 176 + lt * 32 + g * 8);

    const float* featn = feature + ((size_t)n * C_ + h * DH_) * HW_;
    float* outn = out + ((size_t)n * C_ + h * DH_) * HW_;

#pragma unroll
    for (int i = 0; i < 4; ++i) {
        f32x4 s[5];
#pragma unroll
        for (int lt = 0; lt < 5; ++lt)
            s[lt] = __builtin_amdgcn_mfma_f32_16x16x32_bf16(
                kf[lt], qf[i], (f32x4){0.f, 0.f, 0.f, 0.f}, 0, 0, 0);

#pragma unroll
        for (int r = 0; r < 4; ++r)
            if (4 * g + r >= 13) s[4][r] = -3.0e38f;

        float mx = s[0][0];
#pragma unroll
        for (int lt = 0; lt < 5; ++lt)
#pragma unroll
            for (int r = 0; r < 4; ++r) mx = fmaxf(mx, s[lt][r]);
        mx = fmaxf(mx, __shfl_xor(mx, 16));
        mx = fmaxf(mx, __shfl_xor(mx, 32));

        float Z = 0.f;
#pragma unroll
        for (int lt = 0; lt < 5; ++lt)
#pragma unroll
            for (int r = 0; r < 4; ++r) {
                float e = __expf(s[lt][r] - mx);
                s[lt][r] = e;
                Z += e;
            }
        Z += __shfl_xor(Z, 16);
        Z += __shfl_xor(Z, 32);
        const float inv = 1.f / Z;

        unsigned int pk[5][2];
#pragma unroll
        for (int lt = 0; lt < 5; ++lt) {
            pk[lt][0] = (unsigned int)f2bf(s[lt][0] * inv)
                      | ((unsigned int)f2bf(s[lt][1] * inv) << 16);
            pk[lt][1] = (unsigned int)f2bf(s[lt][2] * inv)
                      | ((unsigned int)f2bf(s[lt][3] * inv) << 16);
        }

        f32x4 pv[2];
        pv[0] = (f32x4){0.f, 0.f, 0.f, 0.f};
        pv[1] = (f32x4){0.f, 0.f, 0.f, 0.f};
#pragma unroll
        for (int lt = 0; lt < 5; ++lt) {
            union { unsigned int u[2]; bf16x4 v; } pa;
            pa.u[0] = pk[lt][0];
            pa.u[1] = pk[lt][1];
#pragma unroll
            for (int dt = 0; dt < 2; ++dt)
                pv[dt] = __builtin_amdgcn_mfma_f32_16x16x16bf16_1k(
                    pa.v, vf[lt][dt], pv[dt], 0, 0, 0);
        }

#pragma unroll
        for (int dt = 0; dt < 2; ++dt) {
            size_t off = (size_t)(dt * 16 + q15) * HW_ + p0 + i * 16 + g * 4;
            float4 f = *(const float4*)&featn[off];
            float4 o;
            o.x = f.x + pv[dt][0];
            o.y = f.y + pv[dt][1];
            o.z = f.z + pv[dt][2];
            o.w = f.w + pv[dt][3];
            *(float4*)&outn[off] = o;
        }
    }
}

// ---------------------------------------------------------------------------
extern "C" void kernel_launch(void* const* d_in, const int* in_sizes, int n_in,
                              void* d_out, int out_size, void* d_ws, size_t ws_size,
                              hipStream_t stream)
{
    const float* feature = (const float*)d_in[0];
    const float* token   = (const float*)d_in[1];
    const float* Wv      = (const float*)d_in[2];
    const float* bv      = (const float*)d_in[3];
    const float* Wk      = (const float*)d_in[4];
    const float* bk      = (const float*)d_in[5];
    const float* Wq      = (const float*)d_in[6];
    const float* bq      = (const float*)d_in[7];
    float* out = (float*)d_out;

    // workspace layout
    float* kvbuf = (float*)d_ws;                                   // NLP_*1024 f32
    unsigned short* tokT = (unsigned short*)(kvbuf + (size_t)NLP_ * 1024);  // NLP_*512 bf16
    unsigned short* Wkv  = tokT + (size_t)NLP_ * 512;              // 1024*512 bf16
    float* bkv = (float*)(Wkv + (size_t)1024 * 512);               // 1024 f32
    unsigned short* qbuf = (unsigned short*)(bkv + 1024);          // N*C*HW bf16 [n][o][p]

    prep_kernel<<<288, 256, 0, stream>>>(token, Wk, bk, Wv, bv, tokT, Wkv, bkv);
    kvgemm_kernel<<<312, 256, 0, stream>>>(tokT, Wkv, bkv, kvbuf);
    qmfma_kernel<<<N_ * 32, 512, 0, stream>>>(feature, Wq, bq, qbuf);
    attn_kernel<<<N_ * HEAD_ * 4, 256, 0, stream>>>(feature, kvbuf, qbuf, out);

    // tuple output: token passthrough
    hipMemcpyAsync(out + (size_t)N_ * C_ * HW_, token,
                   (size_t)N_ * L_ * CT_ * sizeof(float),
                   hipMemcpyDeviceToDevice, stream);
}